// Round 5
// baseline (68.858 us; speedup 1.0000x reference)
//
#include <hip/hip_runtime.h>
#include <hip/hip_fp16.h>

#define NV 2
#define NC 64
#define NH 128
#define NW 416
#define NHW (NH * NW)          // 53248
#define NPT 262144
#define HWBLK (NHW / 64)       // 832

typedef int   vint4  __attribute__((ext_vector_type(4)));
typedef float vfloat4 __attribute__((ext_vector_type(4)));

// ---------------- kernel 0: detect mask encoding ----------------
__global__ void sfa_detect(const unsigned char* __restrict__ mask,
                           int* __restrict__ flag) {
    __shared__ int cnt;
    if (threadIdx.x == 0) cnt = 0;
    __syncthreads();
    int local = 0;
    for (int i = threadIdx.x; i < 1024; i += 256)
        if ((i & 3) != 0 && mask[i] != 0) local++;
    if (local) atomicAdd(&cnt, local);
    __syncthreads();
    if (threadIdx.x == 0) flag[0] = (cnt > 8) ? 1 : 0;   // 1 = byte-encoded
}

// ---------------- kernel 1: transpose (V,C,HW) f32 -> (V,HW,C) f16 --------
__global__ __launch_bounds__(256) void sfa_transpose(const float* __restrict__ x2d,
                                                     __half* __restrict__ xT) {
    __shared__ float tile[64][68];
    const int b = blockIdx.x;            // 0 .. NV*HWBLK-1
    const int v = b / HWBLK;
    const int hw0 = (b % HWBLK) * 64;
    const int t = threadIdx.x;
    const int l16 = t & 15;
    const int g = t >> 4;                // 0..15

    const float* src = x2d + (size_t)v * NC * NHW;
#pragma unroll
    for (int k = 0; k < 4; ++k) {
        int c = g + 16 * k;
        float4 val = *(const float4*)(src + (size_t)c * NHW + hw0 + l16 * 4);
        *(float4*)&tile[c][l16 * 4] = val;
    }
    __syncthreads();
    uint2* dst = (uint2*)(xT + ((size_t)v * NHW + hw0) * NC);
#pragma unroll
    for (int k = 0; k < 4; ++k) {
        int j = g + 16 * k;              // pixel within tile
        int c = l16 * 4;                 // first channel
        __half2 h01 = __floats2half2_rn(tile[c + 0][j], tile[c + 1][j]);
        __half2 h23 = __floats2half2_rn(tile[c + 2][j], tile[c + 3][j]);
        uint2 o;
        o.x = *(unsigned*)&h01;
        o.y = *(unsigned*)&h23;
        dst[(size_t)j * 16 + l16] = o;
    }
}

static __device__ __forceinline__ unsigned hadd2u(unsigned a, unsigned b) {
    __half2 r = __hadd2(*(const __half2*)&a, *(const __half2*)&b);
    return *(unsigned*)&r;
}

// ---------------- kernel 2: main SFA ----------------
// 32 points per block, one 8-point group per wave. Lane = (point p, octet q):
// 8 fp16 channels per lane = one dwordx4 gather per pixel. All pix/mask loads
// issued first (nontemporal), then all 8 gathers back-to-back, then compute.
__global__ __launch_bounds__(256) void sfa_main4(const unsigned* __restrict__ xT,
                                                 const int* __restrict__ pix,
                                                 const unsigned char* __restrict__ maskb,
                                                 const int* __restrict__ flagp,
                                                 float* __restrict__ out) {
    __shared__ float tile[64 * 32];
    const int byteMask = flagp[0];
    const int t = threadIdx.x;
    const int lane = t & 63;
    const int q = lane & 7;        // channel octet (ch 8q..8q+7)
    const int p = lane >> 3;       // point within the 8-point group
    const int wv = t >> 6;
    const int n0 = blockIdx.x * 32;
    const int pt = (wv << 3) + p;  // 0..31
    const int n = n0 + pt;

    // ---- phase 0: pix + mask loads (streaming, nontemporal) ----
    const vint4* pp0 = (const vint4*)(pix + ((size_t)n << 3));
    const vint4* pp1 = (const vint4*)(pix + ((size_t)(NPT + n) << 3));
    vint4 a0 = __builtin_nontemporal_load(pp0);
    vint4 b0 = __builtin_nontemporal_load(pp0 + 1);
    vint4 a1 = __builtin_nontemporal_load(pp1);
    vint4 b1 = __builtin_nontemporal_load(pp1 + 1);
    int m00, m01, m02, m03, m10, m11, m12, m13;
    if (byteMask) {
        uchar4 mv0 = *(const uchar4*)(maskb + ((size_t)n << 2));
        uchar4 mv1 = *(const uchar4*)(maskb + ((size_t)(NPT + n) << 2));
        m00 = mv0.x; m01 = mv0.y; m02 = mv0.z; m03 = mv0.w;
        m10 = mv1.x; m11 = mv1.y; m12 = mv1.z; m13 = mv1.w;
    } else {
        vint4 mv0 = __builtin_nontemporal_load(
            (const vint4*)((const int*)maskb + ((size_t)n << 2)));
        vint4 mv1 = __builtin_nontemporal_load(
            (const vint4*)((const int*)maskb + ((size_t)(NPT + n) << 2)));
        m00 = mv0.x; m01 = mv0.y; m02 = mv0.z; m03 = mv0.w;
        m10 = mv1.x; m11 = mv1.y; m12 = mv1.z; m13 = mv1.w;
    }

    // ---- phase 1: all 8 gathers in flight ----
    unsigned i00 = (unsigned)(a0.y * NW + a0.x);
    unsigned i01 = (unsigned)(a0.w * NW + a0.z);
    unsigned i02 = (unsigned)(b0.y * NW + b0.x);
    unsigned i03 = (unsigned)(b0.w * NW + b0.z);
    unsigned i10 = (unsigned)(a1.y * NW + a1.x);
    unsigned i11 = (unsigned)(a1.w * NW + a1.z);
    unsigned i12 = (unsigned)(b1.y * NW + b1.x);
    unsigned i13 = (unsigned)(b1.w * NW + b1.z);
    const unsigned* bu0 = xT + (q << 2);
    const unsigned* bu1 = bu0 + ((size_t)NHW << 5);
    uint4 g00 = *(const uint4*)(bu0 + ((size_t)i00 << 5));
    uint4 g01 = *(const uint4*)(bu0 + ((size_t)i01 << 5));
    uint4 g02 = *(const uint4*)(bu0 + ((size_t)i02 << 5));
    uint4 g03 = *(const uint4*)(bu0 + ((size_t)i03 << 5));
    uint4 g10 = *(const uint4*)(bu1 + ((size_t)i10 << 5));
    uint4 g11 = *(const uint4*)(bu1 + ((size_t)i11 << 5));
    uint4 g12 = *(const uint4*)(bu1 + ((size_t)i12 << 5));
    uint4 g13 = *(const uint4*)(bu1 + ((size_t)i13 << 5));

    // ---- phase 2: masked mean per view ----
    float f[2][8];
    int cv[2];
    {
        g00.x = m00 ? g00.x : 0u; g00.y = m00 ? g00.y : 0u;
        g00.z = m00 ? g00.z : 0u; g00.w = m00 ? g00.w : 0u;
        g01.x = m01 ? g01.x : 0u; g01.y = m01 ? g01.y : 0u;
        g01.z = m01 ? g01.z : 0u; g01.w = m01 ? g01.w : 0u;
        g02.x = m02 ? g02.x : 0u; g02.y = m02 ? g02.y : 0u;
        g02.z = m02 ? g02.z : 0u; g02.w = m02 ? g02.w : 0u;
        g03.x = m03 ? g03.x : 0u; g03.y = m03 ? g03.y : 0u;
        g03.z = m03 ? g03.z : 0u; g03.w = m03 ? g03.w : 0u;
        unsigned s0 = hadd2u(hadd2u(g00.x, g01.x), hadd2u(g02.x, g03.x));
        unsigned s1 = hadd2u(hadd2u(g00.y, g01.y), hadd2u(g02.y, g03.y));
        unsigned s2 = hadd2u(hadd2u(g00.z, g01.z), hadd2u(g02.z, g03.z));
        unsigned s3 = hadd2u(hadd2u(g00.w, g01.w), hadd2u(g02.w, g03.w));
        int c = (m00 ? 1 : 0) + (m01 ? 1 : 0) + (m02 ? 1 : 0) + (m03 ? 1 : 0);
        float rcp = (c == 0) ? 0.f
                  : (c == 1) ? 1.f
                  : (c == 2) ? 0.5f
                  : (c == 3) ? (1.f / 3.f)
                             : 0.25f;
        float2 f01 = __half22float2(*(const __half2*)&s0);
        float2 f23 = __half22float2(*(const __half2*)&s1);
        float2 f45 = __half22float2(*(const __half2*)&s2);
        float2 f67 = __half22float2(*(const __half2*)&s3);
        f[0][0] = f01.x * rcp; f[0][1] = f01.y * rcp;
        f[0][2] = f23.x * rcp; f[0][3] = f23.y * rcp;
        f[0][4] = f45.x * rcp; f[0][5] = f45.y * rcp;
        f[0][6] = f67.x * rcp; f[0][7] = f67.y * rcp;
        cv[0] = c;
    }
    {
        g10.x = m10 ? g10.x : 0u; g10.y = m10 ? g10.y : 0u;
        g10.z = m10 ? g10.z : 0u; g10.w = m10 ? g10.w : 0u;
        g11.x = m11 ? g11.x : 0u; g11.y = m11 ? g11.y : 0u;
        g11.z = m11 ? g11.z : 0u; g11.w = m11 ? g11.w : 0u;
        g12.x = m12 ? g12.x : 0u; g12.y = m12 ? g12.y : 0u;
        g12.z = m12 ? g12.z : 0u; g12.w = m12 ? g12.w : 0u;
        g13.x = m13 ? g13.x : 0u; g13.y = m13 ? g13.y : 0u;
        g13.z = m13 ? g13.z : 0u; g13.w = m13 ? g13.w : 0u;
        unsigned s0 = hadd2u(hadd2u(g10.x, g11.x), hadd2u(g12.x, g13.x));
        unsigned s1 = hadd2u(hadd2u(g10.y, g11.y), hadd2u(g12.y, g13.y));
        unsigned s2 = hadd2u(hadd2u(g10.z, g11.z), hadd2u(g12.z, g13.z));
        unsigned s3 = hadd2u(hadd2u(g10.w, g11.w), hadd2u(g12.w, g13.w));
        int c = (m10 ? 1 : 0) + (m11 ? 1 : 0) + (m12 ? 1 : 0) + (m13 ? 1 : 0);
        float rcp = (c == 0) ? 0.f
                  : (c == 1) ? 1.f
                  : (c == 2) ? 0.5f
                  : (c == 3) ? (1.f / 3.f)
                             : 0.25f;
        float2 f01 = __half22float2(*(const __half2*)&s0);
        float2 f23 = __half22float2(*(const __half2*)&s1);
        float2 f45 = __half22float2(*(const __half2*)&s2);
        float2 f67 = __half22float2(*(const __half2*)&s3);
        f[1][0] = f01.x * rcp; f[1][1] = f01.y * rcp;
        f[1][2] = f23.x * rcp; f[1][3] = f23.y * rcp;
        f[1][4] = f45.x * rcp; f[1][5] = f45.y * rcp;
        f[1][6] = f67.x * rcp; f[1][7] = f67.y * rcp;
        cv[1] = c;
    }

    // ---- phase 3: cosine + combine ----
    float d = 0.f, q0 = 0.f, q1 = 0.f;
#pragma unroll
    for (int j = 0; j < 8; ++j) {
        d  = fmaf(f[0][j], f[1][j], d);
        q0 = fmaf(f[0][j], f[0][j], q0);
        q1 = fmaf(f[1][j], f[1][j], q1);
    }
#pragma unroll
    for (int m = 1; m < 8; m <<= 1) {
        d  += __shfl_xor(d, m, 64);
        q0 += __shfl_xor(q0, m, 64);
        q1 += __shfl_xor(q1, m, 64);
    }
    float cosv = d * rsqrtf(fmaxf(q0 * q1, 1e-16f));
    float w0 = cv[0] > 0 ? 1.f : 0.f;
    float w1 = cv[1] > 0 ? 1.f : 0.f;
    float cw = cosv * w0 * w1;
    float wi = (w0 > w1) ? 1.f : 0.f;
    float wj = (w1 > w0) ? 1.f : 0.f;
    float cw0 = (cw + wi) * 0.5f;
    float cw1 = (cw + wj) * 0.5f;
#pragma unroll
    for (int j = 0; j < 8; ++j) {
        int row = (q << 3) + j;
        tile[(row << 5) + ((pt + row) & 31)] = cw0 * f[0][j] + cw1 * f[1][j];
    }
    __syncthreads();

    // ---- phase 4: coalesced output (nontemporal) ----
    const int c = t >> 2;
    const int s = t & 3;
    float* op = out + (size_t)c * NPT + n0;
#pragma unroll
    for (int k = 0; k < 2; ++k) {
        int j0 = (k << 4) + (s << 2);
        vfloat4 o4;
        o4.x = tile[(c << 5) + ((j0 + 0 + c) & 31)];
        o4.y = tile[(c << 5) + ((j0 + 1 + c) & 31)];
        o4.z = tile[(c << 5) + ((j0 + 2 + c) & 31)];
        o4.w = tile[(c << 5) + ((j0 + 3 + c) & 31)];
        __builtin_nontemporal_store(o4, (vfloat4*)(op + j0));
    }
}

// ---------------- fallback: direct gather from (V,C,H,W) f32 ----------------
__global__ __launch_bounds__(256) void sfa_main_fb(const float* __restrict__ src,
                                                   const int* __restrict__ pix,
                                                   const unsigned char* __restrict__ maskb,
                                                   const int* __restrict__ flagp,
                                                   float* __restrict__ out) {
    __shared__ float tile[64][68];
    const int byteMask = flagp[0];
    const int t = threadIdx.x;
    const int lane = t & 63;
    const int wv = t >> 6;
    const int n0 = blockIdx.x * 64;

    for (int i = 0; i < 16; ++i) {
        const int pt = (wv << 4) + i;
        const int n = n0 + pt;
        float fv[2];
        int cv[2];
#pragma unroll
        for (int v = 0; v < 2; ++v) {
            const int4* pp = (const int4*)(pix + (((size_t)v * NPT + n) << 3));
            int4 a = pp[0];
            int4 b = pp[1];
            int i0 = a.y * NW + a.x;
            int i1 = a.w * NW + a.z;
            int i2 = b.y * NW + b.x;
            int i3 = b.w * NW + b.z;
            int m0, m1, m2, m3;
            size_t moff = ((size_t)v * NPT + n) << 2;
            if (byteMask) {
                uchar4 m = *(const uchar4*)(maskb + moff);
                m0 = m.x; m1 = m.y; m2 = m.z; m3 = m.w;
            } else {
                int4 m = *(const int4*)((const int*)maskb + moff);
                m0 = m.x; m1 = m.y; m2 = m.z; m3 = m.w;
            }
            const float* base = src + (size_t)(v * NC + lane) * NHW;
            float v0 = base[i0], v1 = base[i1], v2 = base[i2], v3 = base[i3];
            float s = (m0 ? v0 : 0.f) + (m1 ? v1 : 0.f) +
                      (m2 ? v2 : 0.f) + (m3 ? v3 : 0.f);
            int c = (m0 ? 1 : 0) + (m1 ? 1 : 0) + (m2 ? 1 : 0) + (m3 ? 1 : 0);
            float rcp = (c == 0) ? 0.f
                      : (c == 1) ? 1.f
                      : (c == 2) ? 0.5f
                      : (c == 3) ? (1.f / 3.f)
                                 : 0.25f;
            fv[v] = s * rcp;
            cv[v] = c;
        }
        float f0 = fv[0], f1 = fv[1];
        float d = f0 * f1, q0 = f0 * f0, q1 = f1 * f1;
#pragma unroll
        for (int m = 1; m < 64; m <<= 1) {
            d  += __shfl_xor(d, m, 64);
            q0 += __shfl_xor(q0, m, 64);
            q1 += __shfl_xor(q1, m, 64);
        }
        float cosv = d * rsqrtf(fmaxf(q0 * q1, 1e-16f));
        float w0 = cv[0] > 0 ? 1.f : 0.f;
        float w1 = cv[1] > 0 ? 1.f : 0.f;
        float cw = cosv * w0 * w1;
        float wi = (w0 > w1) ? 1.f : 0.f;
        float wj = (w1 > w0) ? 1.f : 0.f;
        float o = ((cw + wi) * f0 + (cw + wj) * f1) * 0.5f;
        tile[lane][pt] = o;
    }
    __syncthreads();
    const int c = t >> 2;
    const int jb = (t & 3) << 4;
    float* op = out + (size_t)c * NPT + n0 + jb;
#pragma unroll
    for (int k = 0; k < 4; ++k) {
        float4 o4 = *(const float4*)&tile[c][jb + (k << 2)];
        *(float4*)(op + (k << 2)) = o4;
    }
}

extern "C" void kernel_launch(void* const* d_in, const int* in_sizes, int n_in,
                              void* d_out, int out_size, void* d_ws, size_t ws_size,
                              hipStream_t stream) {
    const float* x2d = (const float*)d_in[0];
    const int* pix = (const int*)d_in[1];
    const unsigned char* mask = (const unsigned char*)d_in[2];
    float* out = (float*)d_out;

    int* flag = (int*)d_ws;
    __half* xT = (__half*)((char*)d_ws + 256);
    const size_t need = 256 + (size_t)NV * NHW * NC * sizeof(__half);

    sfa_detect<<<1, 256, 0, stream>>>(mask, flag);
    if (ws_size >= need) {
        sfa_transpose<<<NV * HWBLK, 256, 0, stream>>>(x2d, xT);
        sfa_main4<<<NPT / 32, 256, 0, stream>>>((const unsigned*)xT, pix, mask,
                                                flag, out);
    } else {
        sfa_main_fb<<<NPT / 64, 256, 0, stream>>>(x2d, pix, mask, flag, out);
    }
}

// Round 6
// 67.651 us; speedup vs baseline: 1.0178x; 1.0178x over previous
//
#include <hip/hip_runtime.h>
#include <hip/hip_fp16.h>

#define NV 2
#define NC 64
#define NH 128
#define NW 416
#define NHW (NH * NW)          // 53248
#define NPT 262144
#define HWBLK (NHW / 64)       // 832

typedef int vint4 __attribute__((ext_vector_type(4)));

// ---------------- kernel 0: detect mask encoding ----------------
__global__ void sfa_detect(const unsigned char* __restrict__ mask,
                           int* __restrict__ flag) {
    __shared__ int cnt;
    if (threadIdx.x == 0) cnt = 0;
    __syncthreads();
    int local = 0;
    for (int i = threadIdx.x; i < 1024; i += 256)
        if ((i & 3) != 0 && mask[i] != 0) local++;
    if (local) atomicAdd(&cnt, local);
    __syncthreads();
    if (threadIdx.x == 0) flag[0] = (cnt > 8) ? 1 : 0;   // 1 = byte-encoded
}

// ---------------- kernel 1: transpose (V,C,HW) f32 -> (V,HW,C) f16 --------
__global__ __launch_bounds__(256) void sfa_transpose(const float* __restrict__ x2d,
                                                     __half* __restrict__ xT) {
    __shared__ float tile[64][68];
    const int b = blockIdx.x;            // 0 .. NV*HWBLK-1
    const int v = b / HWBLK;
    const int hw0 = (b % HWBLK) * 64;
    const int t = threadIdx.x;
    const int l16 = t & 15;
    const int g = t >> 4;                // 0..15

    const float* src = x2d + (size_t)v * NC * NHW;
#pragma unroll
    for (int k = 0; k < 4; ++k) {
        int c = g + 16 * k;
        float4 val = *(const float4*)(src + (size_t)c * NHW + hw0 + l16 * 4);
        *(float4*)&tile[c][l16 * 4] = val;
    }
    __syncthreads();
    uint2* dst = (uint2*)(xT + ((size_t)v * NHW + hw0) * NC);
#pragma unroll
    for (int k = 0; k < 4; ++k) {
        int j = g + 16 * k;              // pixel within tile
        int c = l16 * 4;                 // first channel
        __half2 h01 = __floats2half2_rn(tile[c + 0][j], tile[c + 1][j]);
        __half2 h23 = __floats2half2_rn(tile[c + 2][j], tile[c + 3][j]);
        uint2 o;
        o.x = *(unsigned*)&h01;
        o.y = *(unsigned*)&h23;
        dst[(size_t)j * 16 + l16] = o;
    }
}

static __device__ __forceinline__ unsigned hadd2u(unsigned a, unsigned b) {
    __half2 r = __hadd2(*(const __half2*)&a, *(const __half2*)&b);
    return *(unsigned*)&r;
}

// masked mean of 4 gathered pixels (8 fp16 channels each)
static __device__ __forceinline__ void view_mean(uint4 g0, uint4 g1, uint4 g2,
                                                 uint4 g3, int m0, int m1,
                                                 int m2, int m3, float fo[8],
                                                 int& cnt) {
    g0.x = m0 ? g0.x : 0u; g0.y = m0 ? g0.y : 0u;
    g0.z = m0 ? g0.z : 0u; g0.w = m0 ? g0.w : 0u;
    g1.x = m1 ? g1.x : 0u; g1.y = m1 ? g1.y : 0u;
    g1.z = m1 ? g1.z : 0u; g1.w = m1 ? g1.w : 0u;
    g2.x = m2 ? g2.x : 0u; g2.y = m2 ? g2.y : 0u;
    g2.z = m2 ? g2.z : 0u; g2.w = m2 ? g2.w : 0u;
    g3.x = m3 ? g3.x : 0u; g3.y = m3 ? g3.y : 0u;
    g3.z = m3 ? g3.z : 0u; g3.w = m3 ? g3.w : 0u;
    unsigned s0 = hadd2u(hadd2u(g0.x, g1.x), hadd2u(g2.x, g3.x));
    unsigned s1 = hadd2u(hadd2u(g0.y, g1.y), hadd2u(g2.y, g3.y));
    unsigned s2 = hadd2u(hadd2u(g0.z, g1.z), hadd2u(g2.z, g3.z));
    unsigned s3 = hadd2u(hadd2u(g0.w, g1.w), hadd2u(g2.w, g3.w));
    int c = (m0 ? 1 : 0) + (m1 ? 1 : 0) + (m2 ? 1 : 0) + (m3 ? 1 : 0);
    float rcp = (c == 0) ? 0.f
              : (c == 1) ? 1.f
              : (c == 2) ? 0.5f
              : (c == 3) ? (1.f / 3.f)
                         : 0.25f;
    float2 f01 = __half22float2(*(const __half2*)&s0);
    float2 f23 = __half22float2(*(const __half2*)&s1);
    float2 f45 = __half22float2(*(const __half2*)&s2);
    float2 f67 = __half22float2(*(const __half2*)&s3);
    fo[0] = f01.x * rcp; fo[1] = f01.y * rcp;
    fo[2] = f23.x * rcp; fo[3] = f23.y * rcp;
    fo[4] = f45.x * rcp; fo[5] = f45.y * rcp;
    fo[6] = f67.x * rcp; fo[7] = f67.y * rcp;
    cnt = c;
}

// ---------------- kernel 2: main SFA ----------------
// 64 points per block; lane = (point p, octet q) handles TWO points (pt, pt+32)
// so 16 gather dwordx4 are in flight per wave.
__global__ __launch_bounds__(256, 4) void sfa_main5(const unsigned* __restrict__ xT,
                                                    const int* __restrict__ pix,
                                                    const unsigned char* __restrict__ maskb,
                                                    const int* __restrict__ flagp,
                                                    float* __restrict__ out) {
    __shared__ float tile[64 * 64];
    const int byteMask = flagp[0];
    const int t = threadIdx.x;
    const int lane = t & 63;
    const int q = lane & 7;        // channel octet (ch 8q..8q+7)
    const int p = lane >> 3;       // point within the 8-point group
    const int wv = t >> 6;
    const int n0 = blockIdx.x * 64;
    const int ptA = (wv << 3) + p; // 0..31
    const int ptB = ptA + 32;      // 32..63
    const int nA = n0 + ptA;
    const int nB = n0 + ptB;

    // ---- phase 0: pix + mask loads (independent, issued together) ----
    const vint4* pA0 = (const vint4*)(pix + ((size_t)nA << 3));
    const vint4* pA1 = (const vint4*)(pix + ((size_t)(NPT + nA) << 3));
    const vint4* pB0 = (const vint4*)(pix + ((size_t)nB << 3));
    const vint4* pB1 = (const vint4*)(pix + ((size_t)(NPT + nB) << 3));
    vint4 aA0 = __builtin_nontemporal_load(pA0);
    vint4 bA0 = __builtin_nontemporal_load(pA0 + 1);
    vint4 aA1 = __builtin_nontemporal_load(pA1);
    vint4 bA1 = __builtin_nontemporal_load(pA1 + 1);
    vint4 aB0 = __builtin_nontemporal_load(pB0);
    vint4 bB0 = __builtin_nontemporal_load(pB0 + 1);
    vint4 aB1 = __builtin_nontemporal_load(pB1);
    vint4 bB1 = __builtin_nontemporal_load(pB1 + 1);

    int mA0, mA1, mA2, mA3, mA4, mA5, mA6, mA7;
    int mB0, mB1, mB2, mB3, mB4, mB5, mB6, mB7;
    if (byteMask) {
        unsigned u0 = *(const unsigned*)(maskb + ((size_t)nA << 2));
        unsigned u1 = *(const unsigned*)(maskb + ((size_t)(NPT + nA) << 2));
        unsigned u2 = *(const unsigned*)(maskb + ((size_t)nB << 2));
        unsigned u3 = *(const unsigned*)(maskb + ((size_t)(NPT + nB) << 2));
        mA0 = u0 & 255; mA1 = (u0 >> 8) & 255; mA2 = (u0 >> 16) & 255; mA3 = (u0 >> 24) & 255;
        mA4 = u1 & 255; mA5 = (u1 >> 8) & 255; mA6 = (u1 >> 16) & 255; mA7 = (u1 >> 24) & 255;
        mB0 = u2 & 255; mB1 = (u2 >> 8) & 255; mB2 = (u2 >> 16) & 255; mB3 = (u2 >> 24) & 255;
        mB4 = u3 & 255; mB5 = (u3 >> 8) & 255; mB6 = (u3 >> 16) & 255; mB7 = (u3 >> 24) & 255;
    } else {
        vint4 u0 = __builtin_nontemporal_load(
            (const vint4*)((const int*)maskb + ((size_t)nA << 2)));
        vint4 u1 = __builtin_nontemporal_load(
            (const vint4*)((const int*)maskb + ((size_t)(NPT + nA) << 2)));
        vint4 u2 = __builtin_nontemporal_load(
            (const vint4*)((const int*)maskb + ((size_t)nB << 2)));
        vint4 u3 = __builtin_nontemporal_load(
            (const vint4*)((const int*)maskb + ((size_t)(NPT + nB) << 2)));
        mA0 = u0.x; mA1 = u0.y; mA2 = u0.z; mA3 = u0.w;
        mA4 = u1.x; mA5 = u1.y; mA6 = u1.z; mA7 = u1.w;
        mB0 = u2.x; mB1 = u2.y; mB2 = u2.z; mB3 = u2.w;
        mB4 = u3.x; mB5 = u3.y; mB6 = u3.z; mB7 = u3.w;
    }

    // ---- phase 1: all 16 gathers in flight ----
    unsigned iA00 = (unsigned)(aA0.y * NW + aA0.x);
    unsigned iA01 = (unsigned)(aA0.w * NW + aA0.z);
    unsigned iA02 = (unsigned)(bA0.y * NW + bA0.x);
    unsigned iA03 = (unsigned)(bA0.w * NW + bA0.z);
    unsigned iA10 = (unsigned)(aA1.y * NW + aA1.x);
    unsigned iA11 = (unsigned)(aA1.w * NW + aA1.z);
    unsigned iA12 = (unsigned)(bA1.y * NW + bA1.x);
    unsigned iA13 = (unsigned)(bA1.w * NW + bA1.z);
    unsigned iB00 = (unsigned)(aB0.y * NW + aB0.x);
    unsigned iB01 = (unsigned)(aB0.w * NW + aB0.z);
    unsigned iB02 = (unsigned)(bB0.y * NW + bB0.x);
    unsigned iB03 = (unsigned)(bB0.w * NW + bB0.z);
    unsigned iB10 = (unsigned)(aB1.y * NW + aB1.x);
    unsigned iB11 = (unsigned)(aB1.w * NW + aB1.z);
    unsigned iB12 = (unsigned)(bB1.y * NW + bB1.x);
    unsigned iB13 = (unsigned)(bB1.w * NW + bB1.z);
    const unsigned* bu0 = xT + (q << 2);
    const unsigned* bu1 = bu0 + ((size_t)NHW << 5);
    uint4 gA00 = *(const uint4*)(bu0 + ((size_t)iA00 << 5));
    uint4 gA01 = *(const uint4*)(bu0 + ((size_t)iA01 << 5));
    uint4 gA02 = *(const uint4*)(bu0 + ((size_t)iA02 << 5));
    uint4 gA03 = *(const uint4*)(bu0 + ((size_t)iA03 << 5));
    uint4 gA10 = *(const uint4*)(bu1 + ((size_t)iA10 << 5));
    uint4 gA11 = *(const uint4*)(bu1 + ((size_t)iA11 << 5));
    uint4 gA12 = *(const uint4*)(bu1 + ((size_t)iA12 << 5));
    uint4 gA13 = *(const uint4*)(bu1 + ((size_t)iA13 << 5));
    uint4 gB00 = *(const uint4*)(bu0 + ((size_t)iB00 << 5));
    uint4 gB01 = *(const uint4*)(bu0 + ((size_t)iB01 << 5));
    uint4 gB02 = *(const uint4*)(bu0 + ((size_t)iB02 << 5));
    uint4 gB03 = *(const uint4*)(bu0 + ((size_t)iB03 << 5));
    uint4 gB10 = *(const uint4*)(bu1 + ((size_t)iB10 << 5));
    uint4 gB11 = *(const uint4*)(bu1 + ((size_t)iB11 << 5));
    uint4 gB12 = *(const uint4*)(bu1 + ((size_t)iB12 << 5));
    uint4 gB13 = *(const uint4*)(bu1 + ((size_t)iB13 << 5));
    __builtin_amdgcn_sched_barrier(0);   // keep all loads issued before use

    // ---- phase 2: masked means ----
    float fA[2][8], fB[2][8];
    int cA[2], cB[2];
    view_mean(gA00, gA01, gA02, gA03, mA0, mA1, mA2, mA3, fA[0], cA[0]);
    view_mean(gA10, gA11, gA12, gA13, mA4, mA5, mA6, mA7, fA[1], cA[1]);
    view_mean(gB00, gB01, gB02, gB03, mB0, mB1, mB2, mB3, fB[0], cB[0]);
    view_mean(gB10, gB11, gB12, gB13, mB4, mB5, mB6, mB7, fB[1], cB[1]);

    // ---- phase 3: cosine + combine (A and B interleaved) ----
    float dA = 0.f, q0A = 0.f, q1A = 0.f;
    float dB = 0.f, q0B = 0.f, q1B = 0.f;
#pragma unroll
    for (int j = 0; j < 8; ++j) {
        dA  = fmaf(fA[0][j], fA[1][j], dA);
        q0A = fmaf(fA[0][j], fA[0][j], q0A);
        q1A = fmaf(fA[1][j], fA[1][j], q1A);
        dB  = fmaf(fB[0][j], fB[1][j], dB);
        q0B = fmaf(fB[0][j], fB[0][j], q0B);
        q1B = fmaf(fB[1][j], fB[1][j], q1B);
    }
#pragma unroll
    for (int m = 1; m < 8; m <<= 1) {
        dA  += __shfl_xor(dA, m, 64);
        q0A += __shfl_xor(q0A, m, 64);
        q1A += __shfl_xor(q1A, m, 64);
        dB  += __shfl_xor(dB, m, 64);
        q0B += __shfl_xor(q0B, m, 64);
        q1B += __shfl_xor(q1B, m, 64);
    }
    {
        float cosv = dA * rsqrtf(fmaxf(q0A * q1A, 1e-16f));
        float w0 = cA[0] > 0 ? 1.f : 0.f;
        float w1 = cA[1] > 0 ? 1.f : 0.f;
        float cw = cosv * w0 * w1;
        float wi = (w0 > w1) ? 1.f : 0.f;
        float wj = (w1 > w0) ? 1.f : 0.f;
        float cw0 = (cw + wi) * 0.5f;
        float cw1 = (cw + wj) * 0.5f;
#pragma unroll
        for (int j = 0; j < 8; ++j) {
            int row = (q << 3) + j;
            tile[(row << 6) + ((ptA + row) & 63)] =
                cw0 * fA[0][j] + cw1 * fA[1][j];
        }
    }
    {
        float cosv = dB * rsqrtf(fmaxf(q0B * q1B, 1e-16f));
        float w0 = cB[0] > 0 ? 1.f : 0.f;
        float w1 = cB[1] > 0 ? 1.f : 0.f;
        float cw = cosv * w0 * w1;
        float wi = (w0 > w1) ? 1.f : 0.f;
        float wj = (w1 > w0) ? 1.f : 0.f;
        float cw0 = (cw + wi) * 0.5f;
        float cw1 = (cw + wj) * 0.5f;
#pragma unroll
        for (int j = 0; j < 8; ++j) {
            int row = (q << 3) + j;
            tile[(row << 6) + ((ptB + row) & 63)] =
                cw0 * fB[0][j] + cw1 * fB[1][j];
        }
    }
    __syncthreads();

    // ---- phase 4: coalesced output ----
    const int c = t >> 2;
    const int jb = (t & 3) << 4;
    float* op = out + (size_t)c * NPT + n0 + jb;
#pragma unroll
    for (int k = 0; k < 4; ++k) {
        float4 o4;
        o4.x = tile[(c << 6) + ((jb + (k << 2) + 0 + c) & 63)];
        o4.y = tile[(c << 6) + ((jb + (k << 2) + 1 + c) & 63)];
        o4.z = tile[(c << 6) + ((jb + (k << 2) + 2 + c) & 63)];
        o4.w = tile[(c << 6) + ((jb + (k << 2) + 3 + c) & 63)];
        *(float4*)(op + (k << 2)) = o4;
    }
}

// ---------------- fallback: direct gather from (V,C,H,W) f32 ----------------
__global__ __launch_bounds__(256) void sfa_main_fb(const float* __restrict__ src,
                                                   const int* __restrict__ pix,
                                                   const unsigned char* __restrict__ maskb,
                                                   const int* __restrict__ flagp,
                                                   float* __restrict__ out) {
    __shared__ float tile[64][68];
    const int byteMask = flagp[0];
    const int t = threadIdx.x;
    const int lane = t & 63;
    const int wv = t >> 6;
    const int n0 = blockIdx.x * 64;

    for (int i = 0; i < 16; ++i) {
        const int pt = (wv << 4) + i;
        const int n = n0 + pt;
        float fv[2];
        int cv[2];
#pragma unroll
        for (int v = 0; v < 2; ++v) {
            const int4* pp = (const int4*)(pix + (((size_t)v * NPT + n) << 3));
            int4 a = pp[0];
            int4 b = pp[1];
            int i0 = a.y * NW + a.x;
            int i1 = a.w * NW + a.z;
            int i2 = b.y * NW + b.x;
            int i3 = b.w * NW + b.z;
            int m0, m1, m2, m3;
            size_t moff = ((size_t)v * NPT + n) << 2;
            if (byteMask) {
                uchar4 m = *(const uchar4*)(maskb + moff);
                m0 = m.x; m1 = m.y; m2 = m.z; m3 = m.w;
            } else {
                int4 m = *(const int4*)((const int*)maskb + moff);
                m0 = m.x; m1 = m.y; m2 = m.z; m3 = m.w;
            }
            const float* base = src + (size_t)(v * NC + lane) * NHW;
            float v0 = base[i0], v1 = base[i1], v2 = base[i2], v3 = base[i3];
            float s = (m0 ? v0 : 0.f) + (m1 ? v1 : 0.f) +
                      (m2 ? v2 : 0.f) + (m3 ? v3 : 0.f);
            int c = (m0 ? 1 : 0) + (m1 ? 1 : 0) + (m2 ? 1 : 0) + (m3 ? 1 : 0);
            float rcp = (c == 0) ? 0.f
                      : (c == 1) ? 1.f
                      : (c == 2) ? 0.5f
                      : (c == 3) ? (1.f / 3.f)
                                 : 0.25f;
            fv[v] = s * rcp;
            cv[v] = c;
        }
        float f0 = fv[0], f1 = fv[1];
        float d = f0 * f1, q0 = f0 * f0, q1 = f1 * f1;
#pragma unroll
        for (int m = 1; m < 64; m <<= 1) {
            d  += __shfl_xor(d, m, 64);
            q0 += __shfl_xor(q0, m, 64);
            q1 += __shfl_xor(q1, m, 64);
        }
        float cosv = d * rsqrtf(fmaxf(q0 * q1, 1e-16f));
        float w0 = cv[0] > 0 ? 1.f : 0.f;
        float w1 = cv[1] > 0 ? 1.f : 0.f;
        float cw = cosv * w0 * w1;
        float wi = (w0 > w1) ? 1.f : 0.f;
        float wj = (w1 > w0) ? 1.f : 0.f;
        float o = ((cw + wi) * f0 + (cw + wj) * f1) * 0.5f;
        tile[lane][pt] = o;
    }
    __syncthreads();
    const int c = t >> 2;
    const int jb = (t & 3) << 4;
    float* op = out + (size_t)c * NPT + n0 + jb;
#pragma unroll
    for (int k = 0; k < 4; ++k) {
        float4 o4 = *(const float4*)&tile[c][jb + (k << 2)];
        *(float4*)(op + (k << 2)) = o4;
    }
}

extern "C" void kernel_launch(void* const* d_in, const int* in_sizes, int n_in,
                              void* d_out, int out_size, void* d_ws, size_t ws_size,
                              hipStream_t stream) {
    const float* x2d = (const float*)d_in[0];
    const int* pix = (const int*)d_in[1];
    const unsigned char* mask = (const unsigned char*)d_in[2];
    float* out = (float*)d_out;

    int* flag = (int*)d_ws;
    __half* xT = (__half*)((char*)d_ws + 256);
    const size_t need = 256 + (size_t)NV * NHW * NC * sizeof(__half);

    sfa_detect<<<1, 256, 0, stream>>>(mask, flag);
    if (ws_size >= need) {
        sfa_transpose<<<NV * HWBLK, 256, 0, stream>>>(x2d, xT);
        sfa_main5<<<NPT / 64, 256, 0, stream>>>((const unsigned*)xT, pix, mask,
                                                flag, out);
    } else {
        sfa_main_fb<<<NPT / 64, 256, 0, stream>>>(x2d, pix, mask, flag, out);
    }
}

// Round 7
// 63.522 us; speedup vs baseline: 1.0840x; 1.0650x over previous
//
#include <hip/hip_runtime.h>
#include <hip/hip_fp16.h>

#define NV 2
#define NC 64
#define NH 128
#define NW 416
#define NHW (NH * NW)          // 53248
#define NPT 262144
#define HWBLK (NHW / 64)       // 832

typedef int vint4 __attribute__((ext_vector_type(4)));

// ---------------- kernel 0: detect mask encoding ----------------
__global__ void sfa_detect(const unsigned char* __restrict__ mask,
                           int* __restrict__ flag) {
    __shared__ int cnt;
    if (threadIdx.x == 0) cnt = 0;
    __syncthreads();
    int local = 0;
    for (int i = threadIdx.x; i < 1024; i += 256)
        if ((i & 3) != 0 && mask[i] != 0) local++;
    if (local) atomicAdd(&cnt, local);
    __syncthreads();
    if (threadIdx.x == 0) flag[0] = (cnt > 8) ? 1 : 0;   // 1 = byte-encoded
}

// ---------------- kernel 1: transpose (V,C,HW) f32 -> (V,HW,C) f16 --------
__global__ __launch_bounds__(256) void sfa_transpose(const float* __restrict__ x2d,
                                                     __half* __restrict__ xT) {
    __shared__ float tile[64][68];
    const int b = blockIdx.x;            // 0 .. NV*HWBLK-1
    const int v = b / HWBLK;
    const int hw0 = (b % HWBLK) * 64;
    const int t = threadIdx.x;
    const int l16 = t & 15;
    const int g = t >> 4;                // 0..15

    const float* src = x2d + (size_t)v * NC * NHW;
#pragma unroll
    for (int k = 0; k < 4; ++k) {
        int c = g + 16 * k;
        float4 val = *(const float4*)(src + (size_t)c * NHW + hw0 + l16 * 4);
        *(float4*)&tile[c][l16 * 4] = val;
    }
    __syncthreads();
    uint2* dst = (uint2*)(xT + ((size_t)v * NHW + hw0) * NC);
#pragma unroll
    for (int k = 0; k < 4; ++k) {
        int j = g + 16 * k;              // pixel within tile
        int c = l16 * 4;                 // first channel
        __half2 h01 = __floats2half2_rn(tile[c + 0][j], tile[c + 1][j]);
        __half2 h23 = __floats2half2_rn(tile[c + 2][j], tile[c + 3][j]);
        uint2 o;
        o.x = *(unsigned*)&h01;
        o.y = *(unsigned*)&h23;
        dst[(size_t)j * 16 + l16] = o;
    }
}

static __device__ __forceinline__ unsigned hadd2u(unsigned a, unsigned b) {
    __half2 r = __hadd2(*(const __half2*)&a, *(const __half2*)&b);
    return *(unsigned*)&r;
}

// masked mean of 4 gathered pixels (8 fp16 channels each)
static __device__ __forceinline__ void view_mean(uint4 g0, uint4 g1, uint4 g2,
                                                 uint4 g3, int m0, int m1,
                                                 int m2, int m3, float fo[8],
                                                 int& cnt) {
    g0.x = m0 ? g0.x : 0u; g0.y = m0 ? g0.y : 0u;
    g0.z = m0 ? g0.z : 0u; g0.w = m0 ? g0.w : 0u;
    g1.x = m1 ? g1.x : 0u; g1.y = m1 ? g1.y : 0u;
    g1.z = m1 ? g1.z : 0u; g1.w = m1 ? g1.w : 0u;
    g2.x = m2 ? g2.x : 0u; g2.y = m2 ? g2.y : 0u;
    g2.z = m2 ? g2.z : 0u; g2.w = m2 ? g2.w : 0u;
    g3.x = m3 ? g3.x : 0u; g3.y = m3 ? g3.y : 0u;
    g3.z = m3 ? g3.z : 0u; g3.w = m3 ? g3.w : 0u;
    unsigned s0 = hadd2u(hadd2u(g0.x, g1.x), hadd2u(g2.x, g3.x));
    unsigned s1 = hadd2u(hadd2u(g0.y, g1.y), hadd2u(g2.y, g3.y));
    unsigned s2 = hadd2u(hadd2u(g0.z, g1.z), hadd2u(g2.z, g3.z));
    unsigned s3 = hadd2u(hadd2u(g0.w, g1.w), hadd2u(g2.w, g3.w));
    int c = (m0 ? 1 : 0) + (m1 ? 1 : 0) + (m2 ? 1 : 0) + (m3 ? 1 : 0);
    float rcp = (c == 0) ? 0.f
              : (c == 1) ? 1.f
              : (c == 2) ? 0.5f
              : (c == 3) ? (1.f / 3.f)
                         : 0.25f;
    float2 f01 = __half22float2(*(const __half2*)&s0);
    float2 f23 = __half22float2(*(const __half2*)&s1);
    float2 f45 = __half22float2(*(const __half2*)&s2);
    float2 f67 = __half22float2(*(const __half2*)&s3);
    fo[0] = f01.x * rcp; fo[1] = f01.y * rcp;
    fo[2] = f23.x * rcp; fo[3] = f23.y * rcp;
    fo[4] = f45.x * rcp; fo[5] = f45.y * rcp;
    fo[6] = f67.x * rcp; fo[7] = f67.y * rcp;
    cnt = c;
}

// ---------------- kernel 2: main SFA (view-phased gathers) ----------------
// 32 points per block, one 8-point group per wave, 8 fp16 channels per lane.
// Gathers are phased by view: all waves gather view-0 first (active working
// set 6.8 MB, better L2 hit), consume, then view-1.
__global__ __launch_bounds__(256) void sfa_main6(const unsigned* __restrict__ xT,
                                                 const int* __restrict__ pix,
                                                 const unsigned char* __restrict__ maskb,
                                                 const int* __restrict__ flagp,
                                                 float* __restrict__ out) {
    __shared__ float tile[64 * 32];
    const int byteMask = flagp[0];
    const int t = threadIdx.x;
    const int lane = t & 63;
    const int q = lane & 7;        // channel octet (ch 8q..8q+7)
    const int p = lane >> 3;       // point within the 8-point group
    const int wv = t >> 6;
    const int n0 = blockIdx.x * 32;
    const int pt = (wv << 3) + p;  // 0..31
    const int n = n0 + pt;

    // ---- phase 0: all pix + mask loads upfront (streaming, nontemporal) ----
    const vint4* pp0 = (const vint4*)(pix + ((size_t)n << 3));
    const vint4* pp1 = (const vint4*)(pix + ((size_t)(NPT + n) << 3));
    vint4 a0 = __builtin_nontemporal_load(pp0);
    vint4 b0 = __builtin_nontemporal_load(pp0 + 1);
    vint4 a1 = __builtin_nontemporal_load(pp1);
    vint4 b1 = __builtin_nontemporal_load(pp1 + 1);
    int m00, m01, m02, m03, m10, m11, m12, m13;
    if (byteMask) {
        unsigned u0 = *(const unsigned*)(maskb + ((size_t)n << 2));
        unsigned u1 = *(const unsigned*)(maskb + ((size_t)(NPT + n) << 2));
        m00 = u0 & 255; m01 = (u0 >> 8) & 255;
        m02 = (u0 >> 16) & 255; m03 = (u0 >> 24) & 255;
        m10 = u1 & 255; m11 = (u1 >> 8) & 255;
        m12 = (u1 >> 16) & 255; m13 = (u1 >> 24) & 255;
    } else {
        vint4 mv0 = __builtin_nontemporal_load(
            (const vint4*)((const int*)maskb + ((size_t)n << 2)));
        vint4 mv1 = __builtin_nontemporal_load(
            (const vint4*)((const int*)maskb + ((size_t)(NPT + n) << 2)));
        m00 = mv0.x; m01 = mv0.y; m02 = mv0.z; m03 = mv0.w;
        m10 = mv1.x; m11 = mv1.y; m12 = mv1.z; m13 = mv1.w;
    }

    float f[2][8];
    int cv[2];

    // ---- phase A: view-0 gathers + consume ----
    {
        unsigned i0 = (unsigned)(a0.y * NW + a0.x);
        unsigned i1 = (unsigned)(a0.w * NW + a0.z);
        unsigned i2 = (unsigned)(b0.y * NW + b0.x);
        unsigned i3 = (unsigned)(b0.w * NW + b0.z);
        const unsigned* bu = xT + (q << 2);
        uint4 g0 = *(const uint4*)(bu + ((size_t)i0 << 5));
        uint4 g1 = *(const uint4*)(bu + ((size_t)i1 << 5));
        uint4 g2 = *(const uint4*)(bu + ((size_t)i2 << 5));
        uint4 g3 = *(const uint4*)(bu + ((size_t)i3 << 5));
        view_mean(g0, g1, g2, g3, m00, m01, m02, m03, f[0], cv[0]);
    }
    __builtin_amdgcn_sched_barrier(0);   // keep view phases separated

    // ---- phase B: view-1 gathers + consume ----
    {
        unsigned i0 = (unsigned)(a1.y * NW + a1.x);
        unsigned i1 = (unsigned)(a1.w * NW + a1.z);
        unsigned i2 = (unsigned)(b1.y * NW + b1.x);
        unsigned i3 = (unsigned)(b1.w * NW + b1.z);
        const unsigned* bu = xT + ((size_t)NHW << 5) + (q << 2);
        uint4 g0 = *(const uint4*)(bu + ((size_t)i0 << 5));
        uint4 g1 = *(const uint4*)(bu + ((size_t)i1 << 5));
        uint4 g2 = *(const uint4*)(bu + ((size_t)i2 << 5));
        uint4 g3 = *(const uint4*)(bu + ((size_t)i3 << 5));
        view_mean(g0, g1, g2, g3, m10, m11, m12, m13, f[1], cv[1]);
    }

    // ---- phase C: cosine + combine ----
    float d = 0.f, q0 = 0.f, q1 = 0.f;
#pragma unroll
    for (int j = 0; j < 8; ++j) {
        d  = fmaf(f[0][j], f[1][j], d);
        q0 = fmaf(f[0][j], f[0][j], q0);
        q1 = fmaf(f[1][j], f[1][j], q1);
    }
#pragma unroll
    for (int m = 1; m < 8; m <<= 1) {
        d  += __shfl_xor(d, m, 64);
        q0 += __shfl_xor(q0, m, 64);
        q1 += __shfl_xor(q1, m, 64);
    }
    float cosv = d * rsqrtf(fmaxf(q0 * q1, 1e-16f));
    float w0 = cv[0] > 0 ? 1.f : 0.f;
    float w1 = cv[1] > 0 ? 1.f : 0.f;
    float cw = cosv * w0 * w1;
    float wi = (w0 > w1) ? 1.f : 0.f;
    float wj = (w1 > w0) ? 1.f : 0.f;
    float cw0 = (cw + wi) * 0.5f;
    float cw1 = (cw + wj) * 0.5f;
#pragma unroll
    for (int j = 0; j < 8; ++j) {
        int row = (q << 3) + j;
        tile[(row << 5) + ((pt + row) & 31)] = cw0 * f[0][j] + cw1 * f[1][j];
    }
    __syncthreads();

    // ---- phase D: coalesced output ----
    const int c = t >> 2;
    const int s = t & 3;
    float* op = out + (size_t)c * NPT + n0;
#pragma unroll
    for (int k = 0; k < 2; ++k) {
        int j0 = (k << 4) + (s << 2);
        float4 o4;
        o4.x = tile[(c << 5) + ((j0 + 0 + c) & 31)];
        o4.y = tile[(c << 5) + ((j0 + 1 + c) & 31)];
        o4.z = tile[(c << 5) + ((j0 + 2 + c) & 31)];
        o4.w = tile[(c << 5) + ((j0 + 3 + c) & 31)];
        *(float4*)(op + j0) = o4;
    }
}

// ---------------- fallback: direct gather from (V,C,H,W) f32 ----------------
__global__ __launch_bounds__(256) void sfa_main_fb(const float* __restrict__ src,
                                                   const int* __restrict__ pix,
                                                   const unsigned char* __restrict__ maskb,
                                                   const int* __restrict__ flagp,
                                                   float* __restrict__ out) {
    __shared__ float tile[64][68];
    const int byteMask = flagp[0];
    const int t = threadIdx.x;
    const int lane = t & 63;
    const int wv = t >> 6;
    const int n0 = blockIdx.x * 64;

    for (int i = 0; i < 16; ++i) {
        const int pt = (wv << 4) + i;
        const int n = n0 + pt;
        float fv[2];
        int cv[2];
#pragma unroll
        for (int v = 0; v < 2; ++v) {
            const int4* pp = (const int4*)(pix + (((size_t)v * NPT + n) << 3));
            int4 a = pp[0];
            int4 b = pp[1];
            int i0 = a.y * NW + a.x;
            int i1 = a.w * NW + a.z;
            int i2 = b.y * NW + b.x;
            int i3 = b.w * NW + b.z;
            int m0, m1, m2, m3;
            size_t moff = ((size_t)v * NPT + n) << 2;
            if (byteMask) {
                uchar4 m = *(const uchar4*)(maskb + moff);
                m0 = m.x; m1 = m.y; m2 = m.z; m3 = m.w;
            } else {
                int4 m = *(const int4*)((const int*)maskb + moff);
                m0 = m.x; m1 = m.y; m2 = m.z; m3 = m.w;
            }
            const float* base = src + (size_t)(v * NC + lane) * NHW;
            float v0 = base[i0], v1 = base[i1], v2 = base[i2], v3 = base[i3];
            float s = (m0 ? v0 : 0.f) + (m1 ? v1 : 0.f) +
                      (m2 ? v2 : 0.f) + (m3 ? v3 : 0.f);
            int c = (m0 ? 1 : 0) + (m1 ? 1 : 0) + (m2 ? 1 : 0) + (m3 ? 1 : 0);
            float rcp = (c == 0) ? 0.f
                      : (c == 1) ? 1.f
                      : (c == 2) ? 0.5f
                      : (c == 3) ? (1.f / 3.f)
                                 : 0.25f;
            fv[v] = s * rcp;
            cv[v] = c;
        }
        float f0 = fv[0], f1 = fv[1];
        float d = f0 * f1, q0 = f0 * f0, q1 = f1 * f1;
#pragma unroll
        for (int m = 1; m < 64; m <<= 1) {
            d  += __shfl_xor(d, m, 64);
            q0 += __shfl_xor(q0, m, 64);
            q1 += __shfl_xor(q1, m, 64);
        }
        float cosv = d * rsqrtf(fmaxf(q0 * q1, 1e-16f));
        float w0 = cv[0] > 0 ? 1.f : 0.f;
        float w1 = cv[1] > 0 ? 1.f : 0.f;
        float cw = cosv * w0 * w1;
        float wi = (w0 > w1) ? 1.f : 0.f;
        float wj = (w1 > w0) ? 1.f : 0.f;
        float o = ((cw + wi) * f0 + (cw + wj) * f1) * 0.5f;
        tile[lane][pt] = o;
    }
    __syncthreads();
    const int c = t >> 2;
    const int jb = (t & 3) << 4;
    float* op = out + (size_t)c * NPT + n0 + jb;
#pragma unroll
    for (int k = 0; k < 4; ++k) {
        float4 o4 = *(const float4*)&tile[c][jb + (k << 2)];
        *(float4*)(op + (k << 2)) = o4;
    }
}

extern "C" void kernel_launch(void* const* d_in, const int* in_sizes, int n_in,
                              void* d_out, int out_size, void* d_ws, size_t ws_size,
                              hipStream_t stream) {
    const float* x2d = (const float*)d_in[0];
    const int* pix = (const int*)d_in[1];
    const unsigned char* mask = (const unsigned char*)d_in[2];
    float* out = (float*)d_out;

    int* flag = (int*)d_ws;
    __half* xT = (__half*)((char*)d_ws + 256);
    const size_t need = 256 + (size_t)NV * NHW * NC * sizeof(__half);

    sfa_detect<<<1, 256, 0, stream>>>(mask, flag);
    if (ws_size >= need) {
        sfa_transpose<<<NV * HWBLK, 256, 0, stream>>>(x2d, xT);
        sfa_main6<<<NPT / 32, 256, 0, stream>>>((const unsigned*)xT, pix, mask,
                                                flag, out);
    } else {
        sfa_main_fb<<<NPT / 64, 256, 0, stream>>>(x2d, pix, mask, flag, out);
    }
}

// Round 8
// 62.267 us; speedup vs baseline: 1.1058x; 1.0201x over previous
//
#include <hip/hip_runtime.h>
#include <hip/hip_fp16.h>

#define NV 2
#define NC 64
#define NH 128
#define NW 416
#define NHW (NH * NW)          // 53248
#define NPT 262144
#define HWBLK (NHW / 64)       // 832

typedef int vint4 __attribute__((ext_vector_type(4)));

// ------------- kernel 1: transpose (V,C,HW) f32 -> (V,HW,C) f16 ------------
// Last block (b == NV*HWBLK) instead detects the mask encoding.
__global__ __launch_bounds__(256) void sfa_transpose_det(
        const float* __restrict__ x2d, __half* __restrict__ xT,
        const unsigned char* __restrict__ mask, int* __restrict__ flag) {
    __shared__ float tile[64][68];
    __shared__ int cnt;
    const int b = blockIdx.x;
    const int t = threadIdx.x;

    if (b == NV * HWBLK) {
        // detect: int32-encoded bool has zero bytes at offsets %4 != 0
        if (t == 0) cnt = 0;
        __syncthreads();
        int local = 0;
        for (int i = t; i < 1024; i += 256)
            if ((i & 3) != 0 && mask[i] != 0) local++;
        if (local) atomicAdd(&cnt, local);
        __syncthreads();
        if (t == 0) flag[0] = (cnt > 8) ? 1 : 0;   // 1 = byte-encoded
        return;
    }

    const int v = b / HWBLK;
    const int hw0 = (b % HWBLK) * 64;
    const int l16 = t & 15;
    const int g = t >> 4;                // 0..15

    const float* src = x2d + (size_t)v * NC * NHW;
#pragma unroll
    for (int k = 0; k < 4; ++k) {
        int c = g + 16 * k;
        float4 val = *(const float4*)(src + (size_t)c * NHW + hw0 + l16 * 4);
        *(float4*)&tile[c][l16 * 4] = val;
    }
    __syncthreads();
    uint2* dst = (uint2*)(xT + ((size_t)v * NHW + hw0) * NC);
#pragma unroll
    for (int k = 0; k < 4; ++k) {
        int j = g + 16 * k;              // pixel within tile
        int c = l16 * 4;                 // first channel
        __half2 h01 = __floats2half2_rn(tile[c + 0][j], tile[c + 1][j]);
        __half2 h23 = __floats2half2_rn(tile[c + 2][j], tile[c + 3][j]);
        uint2 o;
        o.x = *(unsigned*)&h01;
        o.y = *(unsigned*)&h23;
        dst[(size_t)j * 16 + l16] = o;
    }
}

static __device__ __forceinline__ unsigned hadd2u(unsigned a, unsigned b) {
    __half2 r = __hadd2(*(const __half2*)&a, *(const __half2*)&b);
    return *(unsigned*)&r;
}

// masked mean of 4 gathered pixels (8 fp16 channels each)
static __device__ __forceinline__ void view_mean(uint4 g0, uint4 g1, uint4 g2,
                                                 uint4 g3, int m0, int m1,
                                                 int m2, int m3, float fo[8],
                                                 int& cnt) {
    g0.x = m0 ? g0.x : 0u; g0.y = m0 ? g0.y : 0u;
    g0.z = m0 ? g0.z : 0u; g0.w = m0 ? g0.w : 0u;
    g1.x = m1 ? g1.x : 0u; g1.y = m1 ? g1.y : 0u;
    g1.z = m1 ? g1.z : 0u; g1.w = m1 ? g1.w : 0u;
    g2.x = m2 ? g2.x : 0u; g2.y = m2 ? g2.y : 0u;
    g2.z = m2 ? g2.z : 0u; g2.w = m2 ? g2.w : 0u;
    g3.x = m3 ? g3.x : 0u; g3.y = m3 ? g3.y : 0u;
    g3.z = m3 ? g3.z : 0u; g3.w = m3 ? g3.w : 0u;
    unsigned s0 = hadd2u(hadd2u(g0.x, g1.x), hadd2u(g2.x, g3.x));
    unsigned s1 = hadd2u(hadd2u(g0.y, g1.y), hadd2u(g2.y, g3.y));
    unsigned s2 = hadd2u(hadd2u(g0.z, g1.z), hadd2u(g2.z, g3.z));
    unsigned s3 = hadd2u(hadd2u(g0.w, g1.w), hadd2u(g2.w, g3.w));
    int c = (m0 ? 1 : 0) + (m1 ? 1 : 0) + (m2 ? 1 : 0) + (m3 ? 1 : 0);
    float rcp = (c == 0) ? 0.f
              : (c == 1) ? 1.f
              : (c == 2) ? 0.5f
              : (c == 3) ? (1.f / 3.f)
                         : 0.25f;
    float2 f01 = __half22float2(*(const __half2*)&s0);
    float2 f23 = __half22float2(*(const __half2*)&s1);
    float2 f45 = __half22float2(*(const __half2*)&s2);
    float2 f67 = __half22float2(*(const __half2*)&s3);
    fo[0] = f01.x * rcp; fo[1] = f01.y * rcp;
    fo[2] = f23.x * rcp; fo[3] = f23.y * rcp;
    fo[4] = f45.x * rcp; fo[5] = f45.y * rcp;
    fo[6] = f67.x * rcp; fo[7] = f67.y * rcp;
    cnt = c;
}

// ---------------- kernel 2: main SFA ----------------
// 64 points per block as two 32-point tiles (A: pt 0..31, B: pt 32..63).
// Lane = (point p, channel-octet q). View-phased gathers with both tiles
// interleaved: 8 gathers in flight per phase.
__global__ __launch_bounds__(256) void sfa_main7(const unsigned* __restrict__ xT,
                                                 const int* __restrict__ pix,
                                                 const unsigned char* __restrict__ maskb,
                                                 const int* __restrict__ flagp,
                                                 float* __restrict__ out) {
    __shared__ float tile[64 * 64];
    const int byteMask = flagp[0];
    const int t = threadIdx.x;
    const int lane = t & 63;
    const int q = lane & 7;        // channel octet (ch 8q..8q+7)
    const int p = lane >> 3;       // point within the 8-point group
    const int wv = t >> 6;
    const int n0 = blockIdx.x * 64;
    const int ptA = (wv << 3) + p; // 0..31
    const int ptB = ptA + 32;      // 32..63
    const int nA = n0 + ptA;
    const int nB = n0 + ptB;

    // ---- phase 0: all pix + mask loads upfront (nontemporal) ----
    const vint4* ppA0 = (const vint4*)(pix + ((size_t)nA << 3));
    const vint4* ppA1 = (const vint4*)(pix + ((size_t)(NPT + nA) << 3));
    const vint4* ppB0 = (const vint4*)(pix + ((size_t)nB << 3));
    const vint4* ppB1 = (const vint4*)(pix + ((size_t)(NPT + nB) << 3));
    vint4 aA0 = __builtin_nontemporal_load(ppA0);
    vint4 bA0 = __builtin_nontemporal_load(ppA0 + 1);
    vint4 aA1 = __builtin_nontemporal_load(ppA1);
    vint4 bA1 = __builtin_nontemporal_load(ppA1 + 1);
    vint4 aB0 = __builtin_nontemporal_load(ppB0);
    vint4 bB0 = __builtin_nontemporal_load(ppB0 + 1);
    vint4 aB1 = __builtin_nontemporal_load(ppB1);
    vint4 bB1 = __builtin_nontemporal_load(ppB1 + 1);

    int mA0, mA1, mA2, mA3, mA4, mA5, mA6, mA7;
    int mB0, mB1, mB2, mB3, mB4, mB5, mB6, mB7;
    if (byteMask) {
        unsigned u0 = *(const unsigned*)(maskb + ((size_t)nA << 2));
        unsigned u1 = *(const unsigned*)(maskb + ((size_t)(NPT + nA) << 2));
        unsigned u2 = *(const unsigned*)(maskb + ((size_t)nB << 2));
        unsigned u3 = *(const unsigned*)(maskb + ((size_t)(NPT + nB) << 2));
        mA0 = u0 & 255; mA1 = (u0 >> 8) & 255; mA2 = (u0 >> 16) & 255; mA3 = (u0 >> 24) & 255;
        mA4 = u1 & 255; mA5 = (u1 >> 8) & 255; mA6 = (u1 >> 16) & 255; mA7 = (u1 >> 24) & 255;
        mB0 = u2 & 255; mB1 = (u2 >> 8) & 255; mB2 = (u2 >> 16) & 255; mB3 = (u2 >> 24) & 255;
        mB4 = u3 & 255; mB5 = (u3 >> 8) & 255; mB6 = (u3 >> 16) & 255; mB7 = (u3 >> 24) & 255;
    } else {
        vint4 u0 = __builtin_nontemporal_load(
            (const vint4*)((const int*)maskb + ((size_t)nA << 2)));
        vint4 u1 = __builtin_nontemporal_load(
            (const vint4*)((const int*)maskb + ((size_t)(NPT + nA) << 2)));
        vint4 u2 = __builtin_nontemporal_load(
            (const vint4*)((const int*)maskb + ((size_t)nB << 2)));
        vint4 u3 = __builtin_nontemporal_load(
            (const vint4*)((const int*)maskb + ((size_t)(NPT + nB) << 2)));
        mA0 = u0.x; mA1 = u0.y; mA2 = u0.z; mA3 = u0.w;
        mA4 = u1.x; mA5 = u1.y; mA6 = u1.z; mA7 = u1.w;
        mB0 = u2.x; mB1 = u2.y; mB2 = u2.z; mB3 = u2.w;
        mB4 = u3.x; mB5 = u3.y; mB6 = u3.z; mB7 = u3.w;
    }

    float fA[2][8], fB[2][8];
    int cA[2], cB[2];

    // ---- view-0 phase: 8 gathers (tiles A+B) in flight ----
    {
        unsigned iA0 = (unsigned)(aA0.y * NW + aA0.x);
        unsigned iA1 = (unsigned)(aA0.w * NW + aA0.z);
        unsigned iA2 = (unsigned)(bA0.y * NW + bA0.x);
        unsigned iA3 = (unsigned)(bA0.w * NW + bA0.z);
        unsigned iB0 = (unsigned)(aB0.y * NW + aB0.x);
        unsigned iB1 = (unsigned)(aB0.w * NW + aB0.z);
        unsigned iB2 = (unsigned)(bB0.y * NW + bB0.x);
        unsigned iB3 = (unsigned)(bB0.w * NW + bB0.z);
        const unsigned* bu = xT + (q << 2);
        uint4 gA0 = *(const uint4*)(bu + ((size_t)iA0 << 5));
        uint4 gA1 = *(const uint4*)(bu + ((size_t)iA1 << 5));
        uint4 gA2 = *(const uint4*)(bu + ((size_t)iA2 << 5));
        uint4 gA3 = *(const uint4*)(bu + ((size_t)iA3 << 5));
        uint4 gB0 = *(const uint4*)(bu + ((size_t)iB0 << 5));
        uint4 gB1 = *(const uint4*)(bu + ((size_t)iB1 << 5));
        uint4 gB2 = *(const uint4*)(bu + ((size_t)iB2 << 5));
        uint4 gB3 = *(const uint4*)(bu + ((size_t)iB3 << 5));
        view_mean(gA0, gA1, gA2, gA3, mA0, mA1, mA2, mA3, fA[0], cA[0]);
        view_mean(gB0, gB1, gB2, gB3, mB0, mB1, mB2, mB3, fB[0], cB[0]);
    }
    __builtin_amdgcn_sched_barrier(0);   // keep view phases separated

    // ---- view-1 phase: 8 gathers (tiles A+B) in flight ----
    {
        unsigned iA0 = (unsigned)(aA1.y * NW + aA1.x);
        unsigned iA1 = (unsigned)(aA1.w * NW + aA1.z);
        unsigned iA2 = (unsigned)(bA1.y * NW + bA1.x);
        unsigned iA3 = (unsigned)(bA1.w * NW + bA1.z);
        unsigned iB0 = (unsigned)(aB1.y * NW + aB1.x);
        unsigned iB1 = (unsigned)(aB1.w * NW + aB1.z);
        unsigned iB2 = (unsigned)(bB1.y * NW + bB1.x);
        unsigned iB3 = (unsigned)(bB1.w * NW + bB1.z);
        const unsigned* bu = xT + ((size_t)NHW << 5) + (q << 2);
        uint4 gA0 = *(const uint4*)(bu + ((size_t)iA0 << 5));
        uint4 gA1 = *(const uint4*)(bu + ((size_t)iA1 << 5));
        uint4 gA2 = *(const uint4*)(bu + ((size_t)iA2 << 5));
        uint4 gA3 = *(const uint4*)(bu + ((size_t)iA3 << 5));
        uint4 gB0 = *(const uint4*)(bu + ((size_t)iB0 << 5));
        uint4 gB1 = *(const uint4*)(bu + ((size_t)iB1 << 5));
        uint4 gB2 = *(const uint4*)(bu + ((size_t)iB2 << 5));
        uint4 gB3 = *(const uint4*)(bu + ((size_t)iB3 << 5));
        view_mean(gA0, gA1, gA2, gA3, mA4, mA5, mA6, mA7, fA[1], cA[1]);
        view_mean(gB0, gB1, gB2, gB3, mB4, mB5, mB6, mB7, fB[1], cB[1]);
    }

    // ---- reduce + combine (A and B interleaved) ----
    float dA = 0.f, q0A = 0.f, q1A = 0.f;
    float dB = 0.f, q0B = 0.f, q1B = 0.f;
#pragma unroll
    for (int j = 0; j < 8; ++j) {
        dA  = fmaf(fA[0][j], fA[1][j], dA);
        q0A = fmaf(fA[0][j], fA[0][j], q0A);
        q1A = fmaf(fA[1][j], fA[1][j], q1A);
        dB  = fmaf(fB[0][j], fB[1][j], dB);
        q0B = fmaf(fB[0][j], fB[0][j], q0B);
        q1B = fmaf(fB[1][j], fB[1][j], q1B);
    }
#pragma unroll
    for (int m = 1; m < 8; m <<= 1) {
        dA  += __shfl_xor(dA, m, 64);
        q0A += __shfl_xor(q0A, m, 64);
        q1A += __shfl_xor(q1A, m, 64);
        dB  += __shfl_xor(dB, m, 64);
        q0B += __shfl_xor(q0B, m, 64);
        q1B += __shfl_xor(q1B, m, 64);
    }
    {
        float cosv = dA * rsqrtf(fmaxf(q0A * q1A, 1e-16f));
        float w0 = cA[0] > 0 ? 1.f : 0.f;
        float w1 = cA[1] > 0 ? 1.f : 0.f;
        float cw = cosv * w0 * w1;
        float wi = (w0 > w1) ? 1.f : 0.f;
        float wj = (w1 > w0) ? 1.f : 0.f;
        float cw0 = (cw + wi) * 0.5f;
        float cw1 = (cw + wj) * 0.5f;
#pragma unroll
        for (int j = 0; j < 8; ++j) {
            int row = (q << 3) + j;
            tile[(row << 6) + ((ptA + row) & 63)] =
                cw0 * fA[0][j] + cw1 * fA[1][j];
        }
    }
    {
        float cosv = dB * rsqrtf(fmaxf(q0B * q1B, 1e-16f));
        float w0 = cB[0] > 0 ? 1.f : 0.f;
        float w1 = cB[1] > 0 ? 1.f : 0.f;
        float cw = cosv * w0 * w1;
        float wi = (w0 > w1) ? 1.f : 0.f;
        float wj = (w1 > w0) ? 1.f : 0.f;
        float cw0 = (cw + wi) * 0.5f;
        float cw1 = (cw + wj) * 0.5f;
#pragma unroll
        for (int j = 0; j < 8; ++j) {
            int row = (q << 3) + j;
            tile[(row << 6) + ((ptB + row) & 63)] =
                cw0 * fB[0][j] + cw1 * fB[1][j];
        }
    }
    __syncthreads();

    // ---- coalesced output ----
    const int c = t >> 2;
    const int jb = (t & 3) << 4;
    float* op = out + (size_t)c * NPT + n0 + jb;
#pragma unroll
    for (int k = 0; k < 4; ++k) {
        float4 o4;
        o4.x = tile[(c << 6) + ((jb + (k << 2) + 0 + c) & 63)];
        o4.y = tile[(c << 6) + ((jb + (k << 2) + 1 + c) & 63)];
        o4.z = tile[(c << 6) + ((jb + (k << 2) + 2 + c) & 63)];
        o4.w = tile[(c << 6) + ((jb + (k << 2) + 3 + c) & 63)];
        *(float4*)(op + (k << 2)) = o4;
    }
}

// ---------------- fallback: direct gather from (V,C,H,W) f32 ----------------
__global__ __launch_bounds__(256) void sfa_main_fb(const float* __restrict__ src,
                                                   const int* __restrict__ pix,
                                                   const unsigned char* __restrict__ maskb,
                                                   const int* __restrict__ flagp,
                                                   float* __restrict__ out) {
    __shared__ float tile[64][68];
    const int byteMask = flagp[0];
    const int t = threadIdx.x;
    const int lane = t & 63;
    const int wv = t >> 6;
    const int n0 = blockIdx.x * 64;

    for (int i = 0; i < 16; ++i) {
        const int pt = (wv << 4) + i;
        const int n = n0 + pt;
        float fv[2];
        int cv[2];
#pragma unroll
        for (int v = 0; v < 2; ++v) {
            const int4* pp = (const int4*)(pix + (((size_t)v * NPT + n) << 3));
            int4 a = pp[0];
            int4 b = pp[1];
            int i0 = a.y * NW + a.x;
            int i1 = a.w * NW + a.z;
            int i2 = b.y * NW + b.x;
            int i3 = b.w * NW + b.z;
            int m0, m1, m2, m3;
            size_t moff = ((size_t)v * NPT + n) << 2;
            if (byteMask) {
                uchar4 m = *(const uchar4*)(maskb + moff);
                m0 = m.x; m1 = m.y; m2 = m.z; m3 = m.w;
            } else {
                int4 m = *(const int4*)((const int*)maskb + moff);
                m0 = m.x; m1 = m.y; m2 = m.z; m3 = m.w;
            }
            const float* base = src + (size_t)(v * NC + lane) * NHW;
            float v0 = base[i0], v1 = base[i1], v2 = base[i2], v3 = base[i3];
            float s = (m0 ? v0 : 0.f) + (m1 ? v1 : 0.f) +
                      (m2 ? v2 : 0.f) + (m3 ? v3 : 0.f);
            int c = (m0 ? 1 : 0) + (m1 ? 1 : 0) + (m2 ? 1 : 0) + (m3 ? 1 : 0);
            float rcp = (c == 0) ? 0.f
                      : (c == 1) ? 1.f
                      : (c == 2) ? 0.5f
                      : (c == 3) ? (1.f / 3.f)
                                 : 0.25f;
            fv[v] = s * rcp;
            cv[v] = c;
        }
        float f0 = fv[0], f1 = fv[1];
        float d = f0 * f1, q0 = f0 * f0, q1 = f1 * f1;
#pragma unroll
        for (int m = 1; m < 64; m <<= 1) {
            d  += __shfl_xor(d, m, 64);
            q0 += __shfl_xor(q0, m, 64);
            q1 += __shfl_xor(q1, m, 64);
        }
        float cosv = d * rsqrtf(fmaxf(q0 * q1, 1e-16f));
        float w0 = cv[0] > 0 ? 1.f : 0.f;
        float w1 = cv[1] > 0 ? 1.f : 0.f;
        float cw = cosv * w0 * w1;
        float wi = (w0 > w1) ? 1.f : 0.f;
        float wj = (w1 > w0) ? 1.f : 0.f;
        float o = ((cw + wi) * f0 + (cw + wj) * f1) * 0.5f;
        tile[lane][pt] = o;
    }
    __syncthreads();
    const int c = t >> 2;
    const int jb = (t & 3) << 4;
    float* op = out + (size_t)c * NPT + n0 + jb;
#pragma unroll
    for (int k = 0; k < 4; ++k) {
        float4 o4 = *(const float4*)&tile[c][jb + (k << 2)];
        *(float4*)(op + (k << 2)) = o4;
    }
}

extern "C" void kernel_launch(void* const* d_in, const int* in_sizes, int n_in,
                              void* d_out, int out_size, void* d_ws, size_t ws_size,
                              hipStream_t stream) {
    const float* x2d = (const float*)d_in[0];
    const int* pix = (const int*)d_in[1];
    const unsigned char* mask = (const unsigned char*)d_in[2];
    float* out = (float*)d_out;

    int* flag = (int*)d_ws;
    __half* xT = (__half*)((char*)d_ws + 256);
    const size_t need = 256 + (size_t)NV * NHW * NC * sizeof(__half);

    if (ws_size >= need) {
        sfa_transpose_det<<<NV * HWBLK + 1, 256, 0, stream>>>(x2d, xT, mask,
                                                              flag);
        sfa_main7<<<NPT / 64, 256, 0, stream>>>((const unsigned*)xT, pix, mask,
                                                flag, out);
    } else {
        // minimal fallback: detect then direct-gather
        sfa_transpose_det<<<1, 256, 0, stream>>>(x2d, (__half*)nullptr, mask,
                                                 flag);
        sfa_main_fb<<<NPT / 64, 256, 0, stream>>>(x2d, pix, mask, flag, out);
    }
}

// Round 9
// 59.103 us; speedup vs baseline: 1.1651x; 1.0535x over previous
//
#include <hip/hip_runtime.h>
#include <hip/hip_fp16.h>

#define NV 2
#define NC 64
#define NH 128
#define NW 416
#define NHW (NH * NW)          // 53248
#define NPT 262144
#define HWBLK (NHW / 64)       // 832

typedef int vint4 __attribute__((ext_vector_type(4)));

// ------------- kernel 1: transpose (V,C,HW) f32 -> (V,HW,C) f16 ------------
// Last block (b == NV*HWBLK) instead detects the mask encoding.
__global__ __launch_bounds__(256) void sfa_transpose_det(
        const float* __restrict__ x2d, __half* __restrict__ xT,
        const unsigned char* __restrict__ mask, int* __restrict__ flag) {
    __shared__ float tile[64][68];
    __shared__ int cnt;
    const int b = blockIdx.x;
    const int t = threadIdx.x;

    if (b == NV * HWBLK) {
        // detect: int32-encoded bool has zero bytes at offsets %4 != 0
        if (t == 0) cnt = 0;
        __syncthreads();
        int local = 0;
        for (int i = t; i < 1024; i += 256)
            if ((i & 3) != 0 && mask[i] != 0) local++;
        if (local) atomicAdd(&cnt, local);
        __syncthreads();
        if (t == 0) flag[0] = (cnt > 8) ? 1 : 0;   // 1 = byte-encoded
        return;
    }

    const int v = b / HWBLK;
    const int hw0 = (b % HWBLK) * 64;
    const int l16 = t & 15;
    const int g = t >> 4;                // 0..15

    const float* src = x2d + (size_t)v * NC * NHW;
#pragma unroll
    for (int k = 0; k < 4; ++k) {
        int c = g + 16 * k;
        float4 val = *(const float4*)(src + (size_t)c * NHW + hw0 + l16 * 4);
        *(float4*)&tile[c][l16 * 4] = val;
    }
    __syncthreads();
    uint2* dst = (uint2*)(xT + ((size_t)v * NHW + hw0) * NC);
#pragma unroll
    for (int k = 0; k < 4; ++k) {
        int j = g + 16 * k;              // pixel within tile
        int c = l16 * 4;                 // first channel
        __half2 h01 = __floats2half2_rn(tile[c + 0][j], tile[c + 1][j]);
        __half2 h23 = __floats2half2_rn(tile[c + 2][j], tile[c + 3][j]);
        uint2 o;
        o.x = *(unsigned*)&h01;
        o.y = *(unsigned*)&h23;
        dst[(size_t)j * 16 + l16] = o;
    }
}

static __device__ __forceinline__ unsigned hadd2u(unsigned a, unsigned b) {
    __half2 r = __hadd2(*(const __half2*)&a, *(const __half2*)&b);
    return *(unsigned*)&r;
}

// masked mean of 4 gathered pixels (8 fp16 channels each)
static __device__ __forceinline__ void view_mean(uint4 g0, uint4 g1, uint4 g2,
                                                 uint4 g3, int m0, int m1,
                                                 int m2, int m3, float fo[8],
                                                 int& cnt) {
    g0.x = m0 ? g0.x : 0u; g0.y = m0 ? g0.y : 0u;
    g0.z = m0 ? g0.z : 0u; g0.w = m0 ? g0.w : 0u;
    g1.x = m1 ? g1.x : 0u; g1.y = m1 ? g1.y : 0u;
    g1.z = m1 ? g1.z : 0u; g1.w = m1 ? g1.w : 0u;
    g2.x = m2 ? g2.x : 0u; g2.y = m2 ? g2.y : 0u;
    g2.z = m2 ? g2.z : 0u; g2.w = m2 ? g2.w : 0u;
    g3.x = m3 ? g3.x : 0u; g3.y = m3 ? g3.y : 0u;
    g3.z = m3 ? g3.z : 0u; g3.w = m3 ? g3.w : 0u;
    unsigned s0 = hadd2u(hadd2u(g0.x, g1.x), hadd2u(g2.x, g3.x));
    unsigned s1 = hadd2u(hadd2u(g0.y, g1.y), hadd2u(g2.y, g3.y));
    unsigned s2 = hadd2u(hadd2u(g0.z, g1.z), hadd2u(g2.z, g3.z));
    unsigned s3 = hadd2u(hadd2u(g0.w, g1.w), hadd2u(g2.w, g3.w));
    int c = (m0 ? 1 : 0) + (m1 ? 1 : 0) + (m2 ? 1 : 0) + (m3 ? 1 : 0);
    float rcp = (c == 0) ? 0.f
              : (c == 1) ? 1.f
              : (c == 2) ? 0.5f
              : (c == 3) ? (1.f / 3.f)
                         : 0.25f;
    float2 f01 = __half22float2(*(const __half2*)&s0);
    float2 f23 = __half22float2(*(const __half2*)&s1);
    float2 f45 = __half22float2(*(const __half2*)&s2);
    float2 f67 = __half22float2(*(const __half2*)&s3);
    fo[0] = f01.x * rcp; fo[1] = f01.y * rcp;
    fo[2] = f23.x * rcp; fo[3] = f23.y * rcp;
    fo[4] = f45.x * rcp; fo[5] = f45.y * rcp;
    fo[6] = f67.x * rcp; fo[7] = f67.y * rcp;
    cnt = c;
}

// ---------------- kernel 2: main SFA (view-phased gathers) ----------------
// 32 points per block, one 8-point group per wave, 8 fp16 channels per lane.
// Gathers are phased by view: all waves gather view-0 first (active working
// set 6.8 MB, better L2 hit), consume, then view-1.
__global__ __launch_bounds__(256) void sfa_main6(const unsigned* __restrict__ xT,
                                                 const int* __restrict__ pix,
                                                 const unsigned char* __restrict__ maskb,
                                                 const int* __restrict__ flagp,
                                                 float* __restrict__ out) {
    __shared__ float tile[64 * 32];
    const int byteMask = flagp[0];
    const int t = threadIdx.x;
    const int lane = t & 63;
    const int q = lane & 7;        // channel octet (ch 8q..8q+7)
    const int p = lane >> 3;       // point within the 8-point group
    const int wv = t >> 6;
    const int n0 = blockIdx.x * 32;
    const int pt = (wv << 3) + p;  // 0..31
    const int n = n0 + pt;

    // ---- phase 0: all pix + mask loads upfront (streaming, nontemporal) ----
    const vint4* pp0 = (const vint4*)(pix + ((size_t)n << 3));
    const vint4* pp1 = (const vint4*)(pix + ((size_t)(NPT + n) << 3));
    vint4 a0 = __builtin_nontemporal_load(pp0);
    vint4 b0 = __builtin_nontemporal_load(pp0 + 1);
    vint4 a1 = __builtin_nontemporal_load(pp1);
    vint4 b1 = __builtin_nontemporal_load(pp1 + 1);
    int m00, m01, m02, m03, m10, m11, m12, m13;
    if (byteMask) {
        unsigned u0 = *(const unsigned*)(maskb + ((size_t)n << 2));
        unsigned u1 = *(const unsigned*)(maskb + ((size_t)(NPT + n) << 2));
        m00 = u0 & 255; m01 = (u0 >> 8) & 255;
        m02 = (u0 >> 16) & 255; m03 = (u0 >> 24) & 255;
        m10 = u1 & 255; m11 = (u1 >> 8) & 255;
        m12 = (u1 >> 16) & 255; m13 = (u1 >> 24) & 255;
    } else {
        vint4 mv0 = __builtin_nontemporal_load(
            (const vint4*)((const int*)maskb + ((size_t)n << 2)));
        vint4 mv1 = __builtin_nontemporal_load(
            (const vint4*)((const int*)maskb + ((size_t)(NPT + n) << 2)));
        m00 = mv0.x; m01 = mv0.y; m02 = mv0.z; m03 = mv0.w;
        m10 = mv1.x; m11 = mv1.y; m12 = mv1.z; m13 = mv1.w;
    }

    float f[2][8];
    int cv[2];

    // ---- phase A: view-0 gathers + consume ----
    {
        unsigned i0 = (unsigned)(a0.y * NW + a0.x);
        unsigned i1 = (unsigned)(a0.w * NW + a0.z);
        unsigned i2 = (unsigned)(b0.y * NW + b0.x);
        unsigned i3 = (unsigned)(b0.w * NW + b0.z);
        const unsigned* bu = xT + (q << 2);
        uint4 g0 = *(const uint4*)(bu + ((size_t)i0 << 5));
        uint4 g1 = *(const uint4*)(bu + ((size_t)i1 << 5));
        uint4 g2 = *(const uint4*)(bu + ((size_t)i2 << 5));
        uint4 g3 = *(const uint4*)(bu + ((size_t)i3 << 5));
        view_mean(g0, g1, g2, g3, m00, m01, m02, m03, f[0], cv[0]);
    }
    __builtin_amdgcn_sched_barrier(0);   // keep view phases separated

    // ---- phase B: view-1 gathers + consume ----
    {
        unsigned i0 = (unsigned)(a1.y * NW + a1.x);
        unsigned i1 = (unsigned)(a1.w * NW + a1.z);
        unsigned i2 = (unsigned)(b1.y * NW + b1.x);
        unsigned i3 = (unsigned)(b1.w * NW + b1.z);
        const unsigned* bu = xT + ((size_t)NHW << 5) + (q << 2);
        uint4 g0 = *(const uint4*)(bu + ((size_t)i0 << 5));
        uint4 g1 = *(const uint4*)(bu + ((size_t)i1 << 5));
        uint4 g2 = *(const uint4*)(bu + ((size_t)i2 << 5));
        uint4 g3 = *(const uint4*)(bu + ((size_t)i3 << 5));
        view_mean(g0, g1, g2, g3, m10, m11, m12, m13, f[1], cv[1]);
    }

    // ---- phase C: cosine + combine ----
    float d = 0.f, q0 = 0.f, q1 = 0.f;
#pragma unroll
    for (int j = 0; j < 8; ++j) {
        d  = fmaf(f[0][j], f[1][j], d);
        q0 = fmaf(f[0][j], f[0][j], q0);
        q1 = fmaf(f[1][j], f[1][j], q1);
    }
#pragma unroll
    for (int m = 1; m < 8; m <<= 1) {
        d  += __shfl_xor(d, m, 64);
        q0 += __shfl_xor(q0, m, 64);
        q1 += __shfl_xor(q1, m, 64);
    }
    float cosv = d * rsqrtf(fmaxf(q0 * q1, 1e-16f));
    float w0 = cv[0] > 0 ? 1.f : 0.f;
    float w1 = cv[1] > 0 ? 1.f : 0.f;
    float cw = cosv * w0 * w1;
    float wi = (w0 > w1) ? 1.f : 0.f;
    float wj = (w1 > w0) ? 1.f : 0.f;
    float cw0 = (cw + wi) * 0.5f;
    float cw1 = (cw + wj) * 0.5f;
#pragma unroll
    for (int j = 0; j < 8; ++j) {
        int row = (q << 3) + j;
        tile[(row << 5) + ((pt + row) & 31)] = cw0 * f[0][j] + cw1 * f[1][j];
    }
    __syncthreads();

    // ---- phase D: coalesced output ----
    const int c = t >> 2;
    const int s = t & 3;
    float* op = out + (size_t)c * NPT + n0;
#pragma unroll
    for (int k = 0; k < 2; ++k) {
        int j0 = (k << 4) + (s << 2);
        float4 o4;
        o4.x = tile[(c << 5) + ((j0 + 0 + c) & 31)];
        o4.y = tile[(c << 5) + ((j0 + 1 + c) & 31)];
        o4.z = tile[(c << 5) + ((j0 + 2 + c) & 31)];
        o4.w = tile[(c << 5) + ((j0 + 3 + c) & 31)];
        *(float4*)(op + j0) = o4;
    }
}

// ---------------- fallback: direct gather from (V,C,H,W) f32 ----------------
__global__ __launch_bounds__(256) void sfa_main_fb(const float* __restrict__ src,
                                                   const int* __restrict__ pix,
                                                   const unsigned char* __restrict__ maskb,
                                                   const int* __restrict__ flagp,
                                                   float* __restrict__ out) {
    __shared__ float tile[64][68];
    const int byteMask = flagp[0];
    const int t = threadIdx.x;
    const int lane = t & 63;
    const int wv = t >> 6;
    const int n0 = blockIdx.x * 64;

    for (int i = 0; i < 16; ++i) {
        const int pt = (wv << 4) + i;
        const int n = n0 + pt;
        float fv[2];
        int cv[2];
#pragma unroll
        for (int v = 0; v < 2; ++v) {
            const int4* pp = (const int4*)(pix + (((size_t)v * NPT + n) << 3));
            int4 a = pp[0];
            int4 b = pp[1];
            int i0 = a.y * NW + a.x;
            int i1 = a.w * NW + a.z;
            int i2 = b.y * NW + b.x;
            int i3 = b.w * NW + b.z;
            int m0, m1, m2, m3;
            size_t moff = ((size_t)v * NPT + n) << 2;
            if (byteMask) {
                uchar4 m = *(const uchar4*)(maskb + moff);
                m0 = m.x; m1 = m.y; m2 = m.z; m3 = m.w;
            } else {
                int4 m = *(const int4*)((const int*)maskb + moff);
                m0 = m.x; m1 = m.y; m2 = m.z; m3 = m.w;
            }
            const float* base = src + (size_t)(v * NC + lane) * NHW;
            float v0 = base[i0], v1 = base[i1], v2 = base[i2], v3 = base[i3];
            float s = (m0 ? v0 : 0.f) + (m1 ? v1 : 0.f) +
                      (m2 ? v2 : 0.f) + (m3 ? v3 : 0.f);
            int c = (m0 ? 1 : 0) + (m1 ? 1 : 0) + (m2 ? 1 : 0) + (m3 ? 1 : 0);
            float rcp = (c == 0) ? 0.f
                      : (c == 1) ? 1.f
                      : (c == 2) ? 0.5f
                      : (c == 3) ? (1.f / 3.f)
                                 : 0.25f;
            fv[v] = s * rcp;
            cv[v] = c;
        }
        float f0 = fv[0], f1 = fv[1];
        float d = f0 * f1, q0 = f0 * f0, q1 = f1 * f1;
#pragma unroll
        for (int m = 1; m < 64; m <<= 1) {
            d  += __shfl_xor(d, m, 64);
            q0 += __shfl_xor(q0, m, 64);
            q1 += __shfl_xor(q1, m, 64);
        }
        float cosv = d * rsqrtf(fmaxf(q0 * q1, 1e-16f));
        float w0 = cv[0] > 0 ? 1.f : 0.f;
        float w1 = cv[1] > 0 ? 1.f : 0.f;
        float cw = cosv * w0 * w1;
        float wi = (w0 > w1) ? 1.f : 0.f;
        float wj = (w1 > w0) ? 1.f : 0.f;
        float o = ((cw + wi) * f0 + (cw + wj) * f1) * 0.5f;
        tile[lane][pt] = o;
    }
    __syncthreads();
    const int c = t >> 2;
    const int jb = (t & 3) << 4;
    float* op = out + (size_t)c * NPT + n0 + jb;
#pragma unroll
    for (int k = 0; k < 4; ++k) {
        float4 o4 = *(const float4*)&tile[c][jb + (k << 2)];
        *(float4*)(op + (k << 2)) = o4;
    }
}

extern "C" void kernel_launch(void* const* d_in, const int* in_sizes, int n_in,
                              void* d_out, int out_size, void* d_ws, size_t ws_size,
                              hipStream_t stream) {
    const float* x2d = (const float*)d_in[0];
    const int* pix = (const int*)d_in[1];
    const unsigned char* mask = (const unsigned char*)d_in[2];
    float* out = (float*)d_out;

    int* flag = (int*)d_ws;
    __half* xT = (__half*)((char*)d_ws + 256);
    const size_t need = 256 + (size_t)NV * NHW * NC * sizeof(__half);

    if (ws_size >= need) {
        sfa_transpose_det<<<NV * HWBLK + 1, 256, 0, stream>>>(x2d, xT, mask,
                                                              flag);
        sfa_main6<<<NPT / 32, 256, 0, stream>>>((const unsigned*)xT, pix, mask,
                                                flag, out);
    } else {
        // minimal fallback: detect then direct-gather
        sfa_transpose_det<<<1, 256, 0, stream>>>(x2d, (__half*)nullptr, mask,
                                                 flag);
        sfa_main_fb<<<NPT / 64, 256, 0, stream>>>(x2d, pix, mask, flag, out);
    }
}